// Round 5
// baseline (217.084 us; speedup 1.0000x reference)
//
#include <hip/hip_runtime.h>

#define NN 100000
#define NE 3200000
#define HC 16

#define BKT_BITS 7
#define BKT_NODES 128                 // nodes per bucket
#define NB 782                        // ceil(NN / 128)
#define CHUNK 4096                    // fine chunk (hist/offset granularity)
#define NCH 782                       // ceil(NE / CHUNK)
#define CCHUNK 32768                  // coarse chunk for k_place (8 fine)
#define NCC 98                        // ceil(NE / CCHUNK)
#define RANGE 98                      // buckets per range (ceil(NB/8))

// ---------- pass 1: bucket-bin the edges (no global atomics) ----------

__global__ __launch_bounds__(256) void k_hist(const int* __restrict__ dst,
                                              unsigned short* __restrict__ H) {
    __shared__ unsigned h[NB];
    int tid = threadIdx.x;
    for (int j = tid; j < NB; j += 256) h[j] = 0;
    __syncthreads();
    int b0 = blockIdx.x * CHUNK;
    int e1 = min(b0 + CHUNK, NE);
    for (int v = b0 + tid * 4; v + 3 < e1; v += 1024) {
        int4 d4 = *(const int4*)(dst + v);
        atomicAdd(&h[((unsigned)d4.x) >> BKT_BITS], 1u);
        atomicAdd(&h[((unsigned)d4.y) >> BKT_BITS], 1u);
        atomicAdd(&h[((unsigned)d4.z) >> BKT_BITS], 1u);
        atomicAdd(&h[((unsigned)d4.w) >> BKT_BITS], 1u);
    }
    __syncthreads();
    unsigned short* row = H + (size_t)blockIdx.x * NB;
    for (int j = tid; j < NB; j += 256) row[j] = (unsigned short)h[j];
}

// one wave per bucket: exclusive running offsets across chunks, IN PLACE over H
__global__ __launch_bounds__(64) void k_colscan(unsigned short* __restrict__ HO,
                                                unsigned* __restrict__ total) {
    int b = blockIdx.x;
    int lane = threadIdx.x;
    unsigned run = 0;
    for (int c0 = 0; c0 < NCH; c0 += 64) {
        int c = c0 + lane;
        unsigned v = (c < NCH) ? (unsigned)HO[(size_t)c * NB + b] : 0u;
        unsigned sc = v;                       // inclusive wave scan
#pragma unroll
        for (int off = 1; off < 64; off <<= 1) {
            unsigned u = __shfl_up(sc, off, 64);
            if (lane >= off) sc += u;
        }
        if (c < NCH) HO[(size_t)c * NB + b] = (unsigned short)(run + sc - v);
        run += __shfl(sc, 63, 64);
    }
    if (lane == 0) total[b] = run;
}

__global__ __launch_bounds__(1024) void k_base(const unsigned* __restrict__ total,
                                               unsigned* __restrict__ base) {
    __shared__ unsigned s[1024];
    int t = threadIdx.x;
    unsigned v = (t < NB) ? total[t] : 0;
    s[t] = v;
    __syncthreads();
    for (int off = 1; off < 1024; off <<= 1) {
        unsigned u = (t >= off) ? s[t - off] : 0;
        __syncthreads();
        s[t] += u;
        __syncthreads();
    }
    if (t < NB) base[t] = s[t] - v;            // exclusive prefix
}

// 2D: 98 coarse chunks x 8 bucket-ranges. Long runs (coalesced writes) AND
// 784 blocks (occupancy). 8x dst/src re-read is L3-absorbed (FETCH 13MB < 25.6MB
// in R4 proved the edge arrays are L3-resident).
__global__ __launch_bounds__(256) void k_place(const int* __restrict__ src,
                                               const int* __restrict__ dst,
                                               const unsigned short* __restrict__ Off,
                                               const unsigned* __restrict__ base,
                                               unsigned* __restrict__ binned) {
    __shared__ unsigned cur[RANGE];
    int bid = blockIdx.x;
    int c = bid >> 3;                 // coarse chunk
    int r = bid & 7;                  // bucket range
    int lo = r * RANGE;
    int nb = min(RANGE, NB - lo);     // r=7 -> 96 buckets
    int tid = threadIdx.x;
    const unsigned short* row = Off + (size_t)(c * 8) * NB;   // fine chunk c*8 < 782
    for (int j = tid; j < nb; j += 256) cur[j] = base[lo + j] + (unsigned)row[lo + j];
    __syncthreads();
    int b0 = c * CCHUNK;
    int e1 = min(b0 + CCHUNK, NE);
    unsigned ulo = (unsigned)lo, uhi = (unsigned)(lo + nb);
    for (int v = b0 + tid * 4; v + 3 < e1; v += 1024) {
        int4 d4 = *(const int4*)(dst + v);
        int4 s4 = *(const int4*)(src + v);
        const int* dd = (const int*)&d4;
        const int* ss = (const int*)&s4;
#pragma unroll
        for (int k = 0; k < 4; ++k) {
            unsigned d = (unsigned)dd[k];
            unsigned bk = d >> BKT_BITS;
            if (bk >= ulo && bk < uhi) {
                unsigned pos = atomicAdd(&cur[bk - ulo], 1u);   // LDS atomic only
                binned[pos] = (((unsigned)ss[k]) << BKT_BITS) | (d & (BKT_NODES - 1));
            }
        }
    }
}

// ---------- pass 2: per-bucket LDS aggregation ----------

__global__ __launch_bounds__(256) void k_degnode(const unsigned* __restrict__ binned,
                                                 const unsigned* __restrict__ base,
                                                 const unsigned* __restrict__ total,
                                                 const float* __restrict__ x,
                                                 float* __restrict__ dinv,
                                                 float* __restrict__ p) {
    __shared__ unsigned cnt[BKT_NODES];
    int tid = threadIdx.x;
    if (tid < BKT_NODES) cnt[tid] = 0;
    __syncthreads();
    unsigned s0 = base[blockIdx.x], c0 = total[blockIdx.x];
    for (unsigned i = tid; i < c0; i += 256)
        atomicAdd(&cnt[binned[s0 + i] & (BKT_NODES - 1)], 1u);
    __syncthreads();
    int node = blockIdx.x * BKT_NODES + tid;
    if (tid < BKT_NODES && node < NN) {
        float di = rsqrtf((float)(cnt[tid] + 1u));        // +1 self-loop
        dinv[node] = di;
        p[node] = di * x[node];
    }
}

__global__ __launch_bounds__(256) void k_agg1(const unsigned* __restrict__ binned,
                                              const unsigned* __restrict__ base,
                                              const unsigned* __restrict__ total,
                                              const float* __restrict__ dinv,
                                              const float* __restrict__ p,
                                              const float* __restrict__ W1,
                                              const float* __restrict__ b1,
                                              const float* __restrict__ W2,
                                              float2* __restrict__ g) {
    __shared__ float acc[BKT_NODES];
    int tid = threadIdx.x;
    if (tid < BKT_NODES) acc[tid] = 0.f;
    __syncthreads();
    unsigned s0 = base[blockIdx.x], c0 = total[blockIdx.x];
    for (unsigned i = tid; i < c0; i += 256) {
        unsigned e = binned[s0 + i];
        atomicAdd(&acc[e & (BKT_NODES - 1)], p[e >> BKT_BITS]);
    }
    __syncthreads();
    int node = blockIdx.x * BKT_NODES + tid;
    if (tid < BKT_NODES && node < NN) {
        float di = dinv[node];
        float s = di * (acc[tid] + p[node]);              // + self-loop
        float g0 = 0.f, g1 = 0.f;
#pragma unroll
        for (int c = 0; c < HC; ++c) {
            float h = fmaxf(fmaf(s, W1[c], b1[c]), 0.f);
            g0 = fmaf(h, W2[2 * c], g0);
            g1 = fmaf(h, W2[2 * c + 1], g1);
        }
        g[node] = make_float2(di * g0, di * g1);
    }
}

__global__ __launch_bounds__(256) void k_agg2(const unsigned* __restrict__ binned,
                                              const unsigned* __restrict__ base,
                                              const unsigned* __restrict__ total,
                                              const float* __restrict__ dinv,
                                              const float2* __restrict__ g,
                                              const float* __restrict__ b2,
                                              float2* __restrict__ out) {
    __shared__ float ax[BKT_NODES];
    __shared__ float ay[BKT_NODES];
    int tid = threadIdx.x;
    if (tid < BKT_NODES) { ax[tid] = 0.f; ay[tid] = 0.f; }
    __syncthreads();
    unsigned s0 = base[blockIdx.x], c0 = total[blockIdx.x];
    for (unsigned i = tid; i < c0; i += 256) {
        unsigned e = binned[s0 + i];
        float2 v = g[e >> BKT_BITS];
        unsigned l = e & (BKT_NODES - 1);
        atomicAdd(&ax[l], v.x);
        atomicAdd(&ay[l], v.y);
    }
    __syncthreads();
    int node = blockIdx.x * BKT_NODES + tid;
    if (tid < BKT_NODES && node < NN) {
        float di = dinv[node];
        float2 me = g[node];
        out[node] = make_float2(fmaf(di, ax[tid] + me.x, b2[0]),
                                fmaf(di, ay[tid] + me.y, b2[1]));
    }
}

// ---------- fallback: round-1 atomic-scatter path (small ws) ----------

__global__ __launch_bounds__(256) void f_deg(const int* __restrict__ dst,
                                             unsigned int* __restrict__ deg, int E) {
    int i = blockIdx.x * blockDim.x + threadIdx.x;
    if (i < E) atomicAdd(&deg[dst[i]], 1u);
}
__global__ __launch_bounds__(256) void f_node1(const float* __restrict__ x,
                                               const unsigned int* __restrict__ deg,
                                               float* __restrict__ dinv, float* __restrict__ p,
                                               float* __restrict__ t, int N) {
    int i = blockIdx.x * blockDim.x + threadIdx.x;
    if (i < N) {
        float di = rsqrtf((float)(deg[i] + 1u));
        dinv[i] = di; float pi = di * x[i]; p[i] = pi; t[i] = pi;
    }
}
__global__ __launch_bounds__(256) void f_scatter1(const int* __restrict__ src,
                                                  const int* __restrict__ dst,
                                                  const float* __restrict__ p,
                                                  float* __restrict__ t, int E) {
    int i = blockIdx.x * blockDim.x + threadIdx.x;
    if (i < E) atomicAdd(&t[dst[i]], p[src[i]]);
}
__global__ __launch_bounds__(256) void f_node2(const float* __restrict__ dinv,
                                               const float* __restrict__ t,
                                               const float* __restrict__ W1,
                                               const float* __restrict__ b1,
                                               const float* __restrict__ W2,
                                               float2* __restrict__ g,
                                               float2* __restrict__ acc, int N) {
    int i = blockIdx.x * blockDim.x + threadIdx.x;
    if (i < N) {
        float di = dinv[i]; float s = di * t[i];
        float g0 = 0.f, g1 = 0.f;
#pragma unroll
        for (int c = 0; c < HC; ++c) {
            float h = fmaxf(fmaf(s, W1[c], b1[c]), 0.f);
            g0 = fmaf(h, W2[2 * c], g0); g1 = fmaf(h, W2[2 * c + 1], g1);
        }
        float2 gv = make_float2(di * g0, di * g1);
        g[i] = gv; acc[i] = gv;
    }
}
__global__ __launch_bounds__(256) void f_scatter2(const int* __restrict__ src,
                                                  const int* __restrict__ dst,
                                                  const float2* __restrict__ g,
                                                  float* __restrict__ acc, int E) {
    int i = blockIdx.x * blockDim.x + threadIdx.x;
    if (i < E) {
        int s = src[i], d = dst[i];
        float2 gv = g[s];
        atomicAdd(&acc[2 * d], gv.x);
        atomicAdd(&acc[2 * d + 1], gv.y);
    }
}
__global__ __launch_bounds__(256) void f_out(const float* __restrict__ dinv,
                                             const float* __restrict__ b2,
                                             float* __restrict__ out, int N) {
    int i = blockIdx.x * blockDim.x + threadIdx.x;
    if (i < N) {
        float di = dinv[i];
        out[2 * i]     = fmaf(di, out[2 * i],     b2[0]);
        out[2 * i + 1] = fmaf(di, out[2 * i + 1], b2[1]);
    }
}

extern "C" void kernel_launch(void* const* d_in, const int* in_sizes, int n_in,
                              void* d_out, int out_size, void* d_ws, size_t ws_size,
                              hipStream_t stream) {
    const float* x  = (const float*)d_in[0];
    const int* ei   = (const int*)d_in[1];
    const int* src  = ei;
    const int* dst  = ei + NE;
    const float* W1 = (const float*)d_in[2];
    const float* b1 = (const float*)d_in[3];
    const float* W2 = (const float*)d_in[4];
    const float* b2 = (const float*)d_in[5];

    const int BT = 256;
    const int gridE = (NE + BT - 1) / BT;
    const int gridN = (NN + BT - 1) / BT;

    // workspace carve-up. The HO region (u16 hist/offsets, scanned in place)
    // is reused for dinv+p after k_place has consumed it (stream-ordered).
    size_t need = 0;
    auto carve = [&](size_t bytes) { size_t o = need; need += (bytes + 255) & ~(size_t)255; return o; };
    size_t ho_bytes   = (size_t)NCH * NB * 2;               // 1.22 MB
    size_t np_bytes   = 2 * (((size_t)NN * 4 + 255) & ~(size_t)255); // dinv + p
    size_t o_base  = carve(NB * 4);
    size_t o_total = carve(NB * 4);
    size_t o_HO    = carve(ho_bytes > np_bytes ? ho_bytes : np_bytes);
    size_t o_g     = carve((size_t)NN * 8);
    size_t o_bin   = carve((size_t)NE * 4);

    if (ws_size >= need) {
        char* ws = (char*)d_ws;
        unsigned* base   = (unsigned*)(ws + o_base);
        unsigned* total  = (unsigned*)(ws + o_total);
        unsigned short* HO = (unsigned short*)(ws + o_HO);
        float*    dinv   = (float*)(ws + o_HO);             // overlays HO (post-place)
        float*    p      = (float*)(ws + o_HO + (((size_t)NN * 4 + 255) & ~(size_t)255));
        float2*   g      = (float2*)(ws + o_g);
        unsigned* binned = (unsigned*)(ws + o_bin);

        k_hist   <<<NCH, 256, 0, stream>>>(dst, HO);
        k_colscan<<<NB, 64, 0, stream>>>(HO, total);
        k_base   <<<1, 1024, 0, stream>>>(total, base);
        k_place  <<<NCC * 8, 256, 0, stream>>>(src, dst, HO, base, binned);
        k_degnode<<<NB, 256, 0, stream>>>(binned, base, total, x, dinv, p);
        k_agg1   <<<NB, 256, 0, stream>>>(binned, base, total, dinv, p, W1, b1, W2, g);
        k_agg2   <<<NB, 256, 0, stream>>>(binned, base, total, dinv, g, b2, (float2*)d_out);
    } else {
        float* out = (float*)d_out;
        char* ws = (char*)d_ws;
        unsigned int* deg = (unsigned int*)ws;
        float* dinv = (float*)(ws + 1 * sizeof(float) * NN);
        float* p    = (float*)(ws + 2 * sizeof(float) * NN);
        float* t    = (float*)(ws + 3 * sizeof(float) * NN);
        float2* g   = (float2*)(ws + 4 * sizeof(float) * NN);

        hipMemsetAsync(deg, 0, NN * sizeof(unsigned int), stream);
        f_deg<<<gridE, BT, 0, stream>>>(dst, deg, NE);
        f_node1<<<gridN, BT, 0, stream>>>(x, deg, dinv, p, t, NN);
        f_scatter1<<<gridE, BT, 0, stream>>>(src, dst, p, t, NE);
        f_node2<<<gridN, BT, 0, stream>>>(dinv, t, W1, b1, W2, g, (float2*)out, NN);
        f_scatter2<<<gridE, BT, 0, stream>>>(src, dst, g, out, NE);
        f_out<<<gridN, BT, 0, stream>>>(dinv, b2, out, NN);
    }
}

// Round 6
// 206.538 us; speedup vs baseline: 1.0511x; 1.0511x over previous
//
#include <hip/hip_runtime.h>

#define NN 100000
#define NE 3200000
#define HC 16

#define BKT_BITS 7
#define BKT_NODES 128                 // nodes per bucket
#define NB 782                        // ceil(NN / 128)
#define NB1 783                       // NB + sentinel
#define CHUNK_S 8192                  // edges per sort block
#define NCC2 391                      // ceil(NE / CHUNK_S)

// ---------- pass 1: per-chunk counting sort (single read, coalesced write) ----------
// Each block sorts its 8192-edge chunk by dst-bucket entirely in LDS, writes the
// sorted chunk contiguously (full-line stores), plus a u16 offset table row.
// No cross-chunk scan, no re-reads, no global atomics.

__global__ __launch_bounds__(256) void k_sortchunk(const int* __restrict__ src,
                                                   const int* __restrict__ dst,
                                                   unsigned short* __restrict__ Hoff,
                                                   unsigned* __restrict__ binned) {
    __shared__ unsigned h[NB1];           // hist -> exclusive offsets -> cursors
    __shared__ unsigned sorted[CHUNK_S];  // 32 KB payload staging
    __shared__ unsigned wsum[4];
    int tid = threadIdx.x;
    int c = blockIdx.x;
    int b0 = c * CHUNK_S;
    int e1 = min(b0 + CHUNK_S, NE);
    int cnt = e1 - b0;

    for (int j = tid; j < NB1; j += 256) h[j] = 0;
    __syncthreads();

    // histogram (vectorized)
    for (int v = b0 + tid * 4; v < e1; v += 1024) {
        if (v + 3 < e1) {
            int4 d4 = *(const int4*)(dst + v);
            atomicAdd(&h[((unsigned)d4.x) >> BKT_BITS], 1u);
            atomicAdd(&h[((unsigned)d4.y) >> BKT_BITS], 1u);
            atomicAdd(&h[((unsigned)d4.z) >> BKT_BITS], 1u);
            atomicAdd(&h[((unsigned)d4.w) >> BKT_BITS], 1u);
        } else {
            for (int k = v; k < e1; ++k)
                atomicAdd(&h[((unsigned)dst[k]) >> BKT_BITS], 1u);
        }
    }
    __syncthreads();

    // block-wide exclusive scan of h[0..NB1) — 4 cells per thread
    int i0 = tid * 4;
    unsigned v0 = (i0 + 0 < NB1) ? h[i0 + 0] : 0;
    unsigned v1 = (i0 + 1 < NB1) ? h[i0 + 1] : 0;
    unsigned v2 = (i0 + 2 < NB1) ? h[i0 + 2] : 0;
    unsigned v3 = (i0 + 3 < NB1) ? h[i0 + 3] : 0;
    unsigned lsum = v0 + v1 + v2 + v3;
    unsigned sc = lsum;
#pragma unroll
    for (int off = 1; off < 64; off <<= 1) {
        unsigned u = __shfl_up(sc, off, 64);
        if ((tid & 63) >= off) sc += u;
    }
    int wave = tid >> 6;
    if ((tid & 63) == 63) wsum[wave] = sc;
    __syncthreads();
    unsigned wpre = 0;
    for (int w = 0; w < wave; ++w) wpre += wsum[w];
    unsigned excl = wpre + sc - lsum;     // exclusive prefix of this thread's cells
    __syncthreads();                      // everyone done reading old h
    if (i0 + 0 < NB1) h[i0 + 0] = excl;
    if (i0 + 1 < NB1) h[i0 + 1] = excl + v0;
    if (i0 + 2 < NB1) h[i0 + 2] = excl + v0 + v1;
    if (i0 + 3 < NB1) h[i0 + 3] = excl + v0 + v1 + v2;

    // write offset table from registers (no dependence on h after this)
    unsigned short* row = Hoff + (size_t)c * NB1;
    if (i0 + 0 < NB1) row[i0 + 0] = (unsigned short)excl;
    if (i0 + 1 < NB1) row[i0 + 1] = (unsigned short)(excl + v0);
    if (i0 + 2 < NB1) row[i0 + 2] = (unsigned short)(excl + v0 + v1);
    if (i0 + 3 < NB1) row[i0 + 3] = (unsigned short)(excl + v0 + v1 + v2);
    __syncthreads();

    // scatter into LDS using h as cursors
    for (int v = b0 + tid * 4; v < e1; v += 1024) {
        if (v + 3 < e1) {
            int4 d4 = *(const int4*)(dst + v);
            int4 s4 = *(const int4*)(src + v);
            {   unsigned d = (unsigned)d4.x, s = (unsigned)s4.x;
                unsigned pos = atomicAdd(&h[d >> BKT_BITS], 1u);
                sorted[pos] = (s << BKT_BITS) | (d & (BKT_NODES - 1)); }
            {   unsigned d = (unsigned)d4.y, s = (unsigned)s4.y;
                unsigned pos = atomicAdd(&h[d >> BKT_BITS], 1u);
                sorted[pos] = (s << BKT_BITS) | (d & (BKT_NODES - 1)); }
            {   unsigned d = (unsigned)d4.z, s = (unsigned)s4.z;
                unsigned pos = atomicAdd(&h[d >> BKT_BITS], 1u);
                sorted[pos] = (s << BKT_BITS) | (d & (BKT_NODES - 1)); }
            {   unsigned d = (unsigned)d4.w, s = (unsigned)s4.w;
                unsigned pos = atomicAdd(&h[d >> BKT_BITS], 1u);
                sorted[pos] = (s << BKT_BITS) | (d & (BKT_NODES - 1)); }
        } else {
            for (int k = v; k < e1; ++k) {
                unsigned d = (unsigned)dst[k], s = (unsigned)src[k];
                unsigned pos = atomicAdd(&h[d >> BKT_BITS], 1u);
                sorted[pos] = (s << BKT_BITS) | (d & (BKT_NODES - 1));
            }
        }
    }
    __syncthreads();

    // contiguous coalesced write-out
    unsigned* out = binned + (size_t)c * CHUNK_S;
    for (int j = tid * 4; j + 3 < cnt; j += 1024)
        *(int4*)(out + j) = *(const int4*)(sorted + j);
    if (tid == 0)
        for (int j = cnt & ~3; j < cnt; ++j) out[j] = sorted[j];
}

// ---------- pass 2: per-bucket segmented aggregation ----------

__global__ __launch_bounds__(256) void k_deg2(const unsigned* __restrict__ binned,
                                              const unsigned short* __restrict__ Hoff,
                                              const float* __restrict__ x,
                                              float* __restrict__ dinv,
                                              float* __restrict__ p) {
    __shared__ unsigned cnt[BKT_NODES];
    int tid = threadIdx.x, b = blockIdx.x;
    if (tid < BKT_NODES) cnt[tid] = 0;
    __syncthreads();
    for (int c = tid; c < NCC2; c += 256) {
        const unsigned short* row = Hoff + (size_t)c * NB1;
        unsigned off = row[b], end = row[b + 1];
        const unsigned* seg = binned + (size_t)c * CHUNK_S;
        for (unsigned i = off; i < end; ++i)
            atomicAdd(&cnt[seg[i] & (BKT_NODES - 1)], 1u);
    }
    __syncthreads();
    int node = b * BKT_NODES + tid;
    if (tid < BKT_NODES && node < NN) {
        float di = rsqrtf((float)(cnt[tid] + 1u));        // +1 self-loop
        dinv[node] = di;
        p[node] = di * x[node];
    }
}

__global__ __launch_bounds__(256) void k_agg1b(const unsigned* __restrict__ binned,
                                               const unsigned short* __restrict__ Hoff,
                                               const float* __restrict__ dinv,
                                               const float* __restrict__ p,
                                               const float* __restrict__ W1,
                                               const float* __restrict__ b1,
                                               const float* __restrict__ W2,
                                               float2* __restrict__ g) {
    __shared__ float acc[BKT_NODES];
    int tid = threadIdx.x, b = blockIdx.x;
    if (tid < BKT_NODES) acc[tid] = 0.f;
    __syncthreads();
    for (int c = tid; c < NCC2; c += 256) {
        const unsigned short* row = Hoff + (size_t)c * NB1;
        unsigned off = row[b], end = row[b + 1];
        const unsigned* seg = binned + (size_t)c * CHUNK_S;
        for (unsigned i = off; i < end; ++i) {
            unsigned e = seg[i];
            atomicAdd(&acc[e & (BKT_NODES - 1)], p[e >> BKT_BITS]);
        }
    }
    __syncthreads();
    int node = b * BKT_NODES + tid;
    if (tid < BKT_NODES && node < NN) {
        float di = dinv[node];
        float s = di * (acc[tid] + p[node]);              // + self-loop
        float g0 = 0.f, g1 = 0.f;
#pragma unroll
        for (int c = 0; c < HC; ++c) {
            float h = fmaxf(fmaf(s, W1[c], b1[c]), 0.f);
            g0 = fmaf(h, W2[2 * c], g0);
            g1 = fmaf(h, W2[2 * c + 1], g1);
        }
        g[node] = make_float2(di * g0, di * g1);
    }
}

__global__ __launch_bounds__(256) void k_agg2b(const unsigned* __restrict__ binned,
                                               const unsigned short* __restrict__ Hoff,
                                               const float* __restrict__ dinv,
                                               const float2* __restrict__ g,
                                               const float* __restrict__ b2,
                                               float2* __restrict__ out) {
    __shared__ float ax[BKT_NODES];
    __shared__ float ay[BKT_NODES];
    int tid = threadIdx.x, b = blockIdx.x;
    if (tid < BKT_NODES) { ax[tid] = 0.f; ay[tid] = 0.f; }
    __syncthreads();
    for (int c = tid; c < NCC2; c += 256) {
        const unsigned short* row = Hoff + (size_t)c * NB1;
        unsigned off = row[b], end = row[b + 1];
        const unsigned* seg = binned + (size_t)c * CHUNK_S;
        for (unsigned i = off; i < end; ++i) {
            unsigned e = seg[i];
            float2 v = g[e >> BKT_BITS];
            unsigned l = e & (BKT_NODES - 1);
            atomicAdd(&ax[l], v.x);
            atomicAdd(&ay[l], v.y);
        }
    }
    __syncthreads();
    int node = b * BKT_NODES + tid;
    if (tid < BKT_NODES && node < NN) {
        float di = dinv[node];
        float2 me = g[node];
        out[node] = make_float2(fmaf(di, ax[tid] + me.x, b2[0]),
                                fmaf(di, ay[tid] + me.y, b2[1]));
    }
}

// ---------- fallback: round-1 atomic-scatter path (small ws) ----------

__global__ __launch_bounds__(256) void f_deg(const int* __restrict__ dst,
                                             unsigned int* __restrict__ deg, int E) {
    int i = blockIdx.x * blockDim.x + threadIdx.x;
    if (i < E) atomicAdd(&deg[dst[i]], 1u);
}
__global__ __launch_bounds__(256) void f_node1(const float* __restrict__ x,
                                               const unsigned int* __restrict__ deg,
                                               float* __restrict__ dinv, float* __restrict__ p,
                                               float* __restrict__ t, int N) {
    int i = blockIdx.x * blockDim.x + threadIdx.x;
    if (i < N) {
        float di = rsqrtf((float)(deg[i] + 1u));
        dinv[i] = di; float pi = di * x[i]; p[i] = pi; t[i] = pi;
    }
}
__global__ __launch_bounds__(256) void f_scatter1(const int* __restrict__ src,
                                                  const int* __restrict__ dst,
                                                  const float* __restrict__ p,
                                                  float* __restrict__ t, int E) {
    int i = blockIdx.x * blockDim.x + threadIdx.x;
    if (i < E) atomicAdd(&t[dst[i]], p[src[i]]);
}
__global__ __launch_bounds__(256) void f_node2(const float* __restrict__ dinv,
                                               const float* __restrict__ t,
                                               const float* __restrict__ W1,
                                               const float* __restrict__ b1,
                                               const float* __restrict__ W2,
                                               float2* __restrict__ g,
                                               float2* __restrict__ acc, int N) {
    int i = blockIdx.x * blockDim.x + threadIdx.x;
    if (i < N) {
        float di = dinv[i]; float s = di * t[i];
        float g0 = 0.f, g1 = 0.f;
#pragma unroll
        for (int c = 0; c < HC; ++c) {
            float h = fmaxf(fmaf(s, W1[c], b1[c]), 0.f);
            g0 = fmaf(h, W2[2 * c], g0); g1 = fmaf(h, W2[2 * c + 1], g1);
        }
        float2 gv = make_float2(di * g0, di * g1);
        g[i] = gv; acc[i] = gv;
    }
}
__global__ __launch_bounds__(256) void f_scatter2(const int* __restrict__ src,
                                                  const int* __restrict__ dst,
                                                  const float2* __restrict__ g,
                                                  float* __restrict__ acc, int E) {
    int i = blockIdx.x * blockDim.x + threadIdx.x;
    if (i < E) {
        int s = src[i], d = dst[i];
        float2 gv = g[s];
        atomicAdd(&acc[2 * d], gv.x);
        atomicAdd(&acc[2 * d + 1], gv.y);
    }
}
__global__ __launch_bounds__(256) void f_out(const float* __restrict__ dinv,
                                             const float* __restrict__ b2,
                                             float* __restrict__ out, int N) {
    int i = blockIdx.x * blockDim.x + threadIdx.x;
    if (i < N) {
        float di = dinv[i];
        out[2 * i]     = fmaf(di, out[2 * i],     b2[0]);
        out[2 * i + 1] = fmaf(di, out[2 * i + 1], b2[1]);
    }
}

extern "C" void kernel_launch(void* const* d_in, const int* in_sizes, int n_in,
                              void* d_out, int out_size, void* d_ws, size_t ws_size,
                              hipStream_t stream) {
    const float* x  = (const float*)d_in[0];
    const int* ei   = (const int*)d_in[1];
    const int* src  = ei;
    const int* dst  = ei + NE;
    const float* W1 = (const float*)d_in[2];
    const float* b1 = (const float*)d_in[3];
    const float* W2 = (const float*)d_in[4];
    const float* b2 = (const float*)d_in[5];

    const int BT = 256;
    const int gridE = (NE + BT - 1) / BT;
    const int gridN = (NN + BT - 1) / BT;

    size_t need = 0;
    auto carve = [&](size_t bytes) { size_t o = need; need += (bytes + 255) & ~(size_t)255; return o; };
    size_t o_Hoff = carve((size_t)NCC2 * NB1 * 2);          // 612 KB
    size_t o_dinv = carve((size_t)NN * 4);
    size_t o_p    = carve((size_t)NN * 4);
    size_t o_g    = carve((size_t)NN * 8);
    size_t o_bin  = carve((size_t)NCC2 * CHUNK_S * 4);      // 12.8 MB

    if (ws_size >= need) {
        char* ws = (char*)d_ws;
        unsigned short* Hoff = (unsigned short*)(ws + o_Hoff);
        float*    dinv   = (float*)(ws + o_dinv);
        float*    p      = (float*)(ws + o_p);
        float2*   g      = (float2*)(ws + o_g);
        unsigned* binned = (unsigned*)(ws + o_bin);

        k_sortchunk<<<NCC2, 256, 0, stream>>>(src, dst, Hoff, binned);
        k_deg2     <<<NB, 256, 0, stream>>>(binned, Hoff, x, dinv, p);
        k_agg1b    <<<NB, 256, 0, stream>>>(binned, Hoff, dinv, p, W1, b1, W2, g);
        k_agg2b    <<<NB, 256, 0, stream>>>(binned, Hoff, dinv, g, b2, (float2*)d_out);
    } else {
        float* out = (float*)d_out;
        char* ws = (char*)d_ws;
        unsigned int* deg = (unsigned int*)ws;
        float* dinv = (float*)(ws + 1 * sizeof(float) * NN);
        float* p    = (float*)(ws + 2 * sizeof(float) * NN);
        float* t    = (float*)(ws + 3 * sizeof(float) * NN);
        float2* g   = (float2*)(ws + 4 * sizeof(float) * NN);

        hipMemsetAsync(deg, 0, NN * sizeof(unsigned int), stream);
        f_deg<<<gridE, BT, 0, stream>>>(dst, deg, NE);
        f_node1<<<gridN, BT, 0, stream>>>(x, deg, dinv, p, t, NN);
        f_scatter1<<<gridE, BT, 0, stream>>>(src, dst, p, t, NE);
        f_node2<<<gridN, BT, 0, stream>>>(dinv, t, W1, b1, W2, g, (float2*)out, NN);
        f_scatter2<<<gridE, BT, 0, stream>>>(src, dst, g, out, NE);
        f_out<<<gridN, BT, 0, stream>>>(dinv, b2, out, NN);
    }
}

// Round 7
// 193.766 us; speedup vs baseline: 1.1203x; 1.0659x over previous
//
#include <hip/hip_runtime.h>

#define NN 100000
#define NE 3200000
#define HC 16

#define BKT_BITS 7
#define BKT_NODES 128                 // nodes per bucket
#define NB 782                        // ceil(NN / 128) buckets
#define NB1 783                       // NB + sentinel column
#define CHUNK_S 4096                  // edges per sort block
#define NCC2 782                      // ceil(NE / CHUNK_S)
#define NCCP 784                      // padded TH row stride (u16)
#define MCAP 5120                     // merge LDS stage capacity (avg T=4096, max ~4400)

// ---------- pass 1: per-chunk counting sort ----------

__global__ __launch_bounds__(256) void k_sortchunk(const int* __restrict__ src,
                                                   const int* __restrict__ dst,
                                                   unsigned short* __restrict__ Hoff,
                                                   unsigned* __restrict__ binned) {
    __shared__ unsigned h[NB1];           // hist -> exclusive offsets -> cursors
    __shared__ unsigned sorted[CHUNK_S];  // 16 KB payload staging
    __shared__ unsigned wsum[4];
    int tid = threadIdx.x;
    int c = blockIdx.x;
    int b0 = c * CHUNK_S;
    int e1 = min(b0 + CHUNK_S, NE);
    int cnt = e1 - b0;

    for (int j = tid; j < NB1; j += 256) h[j] = 0;
    __syncthreads();

    for (int v = b0 + tid * 4; v + 3 < e1; v += 1024) {
        int4 d4 = *(const int4*)(dst + v);
        atomicAdd(&h[((unsigned)d4.x) >> BKT_BITS], 1u);
        atomicAdd(&h[((unsigned)d4.y) >> BKT_BITS], 1u);
        atomicAdd(&h[((unsigned)d4.z) >> BKT_BITS], 1u);
        atomicAdd(&h[((unsigned)d4.w) >> BKT_BITS], 1u);
    }
    __syncthreads();

    // block-wide exclusive scan of h[0..NB1)
    int i0 = tid * 4;
    unsigned v0 = (i0 + 0 < NB1) ? h[i0 + 0] : 0;
    unsigned v1 = (i0 + 1 < NB1) ? h[i0 + 1] : 0;
    unsigned v2 = (i0 + 2 < NB1) ? h[i0 + 2] : 0;
    unsigned v3 = (i0 + 3 < NB1) ? h[i0 + 3] : 0;
    unsigned lsum = v0 + v1 + v2 + v3;
    unsigned sc = lsum;
#pragma unroll
    for (int off = 1; off < 64; off <<= 1) {
        unsigned u = __shfl_up(sc, off, 64);
        if ((tid & 63) >= off) sc += u;
    }
    int wave = tid >> 6;
    if ((tid & 63) == 63) wsum[wave] = sc;
    __syncthreads();
    unsigned wpre = 0;
    for (int w = 0; w < wave; ++w) wpre += wsum[w];
    unsigned excl = wpre + sc - lsum;
    __syncthreads();
    if (i0 + 0 < NB1) h[i0 + 0] = excl;
    if (i0 + 1 < NB1) h[i0 + 1] = excl + v0;
    if (i0 + 2 < NB1) h[i0 + 2] = excl + v0 + v1;
    if (i0 + 3 < NB1) h[i0 + 3] = excl + v0 + v1 + v2;

    unsigned short* row = Hoff + (size_t)c * NB1;
    if (i0 + 0 < NB1) row[i0 + 0] = (unsigned short)excl;
    if (i0 + 1 < NB1) row[i0 + 1] = (unsigned short)(excl + v0);
    if (i0 + 2 < NB1) row[i0 + 2] = (unsigned short)(excl + v0 + v1);
    if (i0 + 3 < NB1) row[i0 + 3] = (unsigned short)(excl + v0 + v1 + v2);
    __syncthreads();

    for (int v = b0 + tid * 4; v + 3 < e1; v += 1024) {
        int4 d4 = *(const int4*)(dst + v);
        int4 s4 = *(const int4*)(src + v);
        {   unsigned d = (unsigned)d4.x, s = (unsigned)s4.x;
            unsigned pos = atomicAdd(&h[d >> BKT_BITS], 1u);
            sorted[pos] = (s << BKT_BITS) | (d & (BKT_NODES - 1)); }
        {   unsigned d = (unsigned)d4.y, s = (unsigned)s4.y;
            unsigned pos = atomicAdd(&h[d >> BKT_BITS], 1u);
            sorted[pos] = (s << BKT_BITS) | (d & (BKT_NODES - 1)); }
        {   unsigned d = (unsigned)d4.z, s = (unsigned)s4.z;
            unsigned pos = atomicAdd(&h[d >> BKT_BITS], 1u);
            sorted[pos] = (s << BKT_BITS) | (d & (BKT_NODES - 1)); }
        {   unsigned d = (unsigned)d4.w, s = (unsigned)s4.w;
            unsigned pos = atomicAdd(&h[d >> BKT_BITS], 1u);
            sorted[pos] = (s << BKT_BITS) | (d & (BKT_NODES - 1)); }
    }
    __syncthreads();

    unsigned* out = binned + (size_t)c * CHUNK_S;
    for (int j = tid * 4; j + 3 < cnt; j += 1024)
        *(int4*)(out + j) = *(const int4*)(sorted + j);
}

// ---------- pass 2: transpose Hoff[chunk][bucket] -> TH[bucket][chunk] ----------

__global__ __launch_bounds__(256) void k_transT(const unsigned short* __restrict__ Hoff,
                                                unsigned short* __restrict__ TH) {
    __shared__ unsigned short tile[32][33];
    int tx = threadIdx.x & 31;
    int ty0 = (threadIdx.x >> 5) * 4;
    int c0 = blockIdx.x * 32;     // chunk base
    int b0 = blockIdx.y * 32;     // bucket base
#pragma unroll
    for (int k = 0; k < 4; ++k) {
        int c = c0 + ty0 + k, b = b0 + tx;
        tile[ty0 + k][tx] = (c < NCC2 && b < NB1) ? Hoff[(size_t)c * NB1 + b] : (unsigned short)0;
    }
    __syncthreads();
#pragma unroll
    for (int k = 0; k < 4; ++k) {
        int b = b0 + ty0 + k, c = c0 + tx;
        if (b < NB1 && c < NCC2) TH[(size_t)b * NCCP + c] = tile[tx][ty0 + k];
    }
}

// ---------- pass 3: per-bucket totals + global base scan ----------

__global__ __launch_bounds__(64) void k_totals(const unsigned short* __restrict__ TH,
                                               unsigned* __restrict__ totals) {
    int b = blockIdx.x;
    int lane = threadIdx.x;
    const unsigned short* r0 = TH + (size_t)b * NCCP;
    const unsigned short* r1 = r0 + NCCP;
    unsigned s = 0;
    for (int c = lane; c < NCC2; c += 64) s += (unsigned)r1[c] - (unsigned)r0[c];
#pragma unroll
    for (int off = 32; off >= 1; off >>= 1) s += __shfl_xor(s, off, 64);
    if (lane == 0) totals[b] = s;
}

__global__ __launch_bounds__(1024) void k_base2(const unsigned* __restrict__ totals,
                                                unsigned* __restrict__ gbase) {
    __shared__ unsigned s[1024];
    int t = threadIdx.x;
    unsigned v = (t < NB) ? ((totals[t] + 3u) & ~3u) : 0;   // round4 for aligned regions
    s[t] = v;
    __syncthreads();
    for (int off = 1; off < 1024; off <<= 1) {
        unsigned u = (t >= off) ? s[t - off] : 0;
        __syncthreads();
        s[t] += u;
        __syncthreads();
    }
    if (t < NB) gbase[t] = s[t] - v;
}

// ---------- pass 4: merge segments -> contiguous per-bucket runs, fused degree ----------

__global__ __launch_bounds__(256) void k_merge_deg(const unsigned* __restrict__ binned,
                                                   const unsigned short* __restrict__ TH,
                                                   const unsigned* __restrict__ gbase,
                                                   const float* __restrict__ x,
                                                   unsigned* __restrict__ merged,
                                                   float* __restrict__ dinv,
                                                   float* __restrict__ p) {
    __shared__ unsigned short th0s[NCC2];
    __shared__ unsigned short lens[NCC2];
    __shared__ unsigned S[NB1];            // exclusive scan of lens; S[NCC2] = T
    __shared__ unsigned wsum[4];
    __shared__ unsigned cnt[BKT_NODES];
    __shared__ unsigned stage[MCAP];
    int tid = threadIdx.x, b = blockIdx.x;

    const unsigned short* r0 = TH + (size_t)b * NCCP;
    const unsigned short* r1 = r0 + NCCP;
    for (int c = tid; c < NCC2; c += 256) {
        unsigned a = r0[c];
        th0s[c] = (unsigned short)a;
        lens[c] = (unsigned short)((unsigned)r1[c] - a);
    }
    if (tid < BKT_NODES) cnt[tid] = 0;
    __syncthreads();

    // exclusive scan of lens -> S
    int i0 = tid * 4;
    unsigned v0 = (i0 + 0 < NCC2) ? (unsigned)lens[i0 + 0] : 0;
    unsigned v1 = (i0 + 1 < NCC2) ? (unsigned)lens[i0 + 1] : 0;
    unsigned v2 = (i0 + 2 < NCC2) ? (unsigned)lens[i0 + 2] : 0;
    unsigned v3 = (i0 + 3 < NCC2) ? (unsigned)lens[i0 + 3] : 0;
    unsigned lsum = v0 + v1 + v2 + v3;
    unsigned sc = lsum;
#pragma unroll
    for (int off = 1; off < 64; off <<= 1) {
        unsigned u = __shfl_up(sc, off, 64);
        if ((tid & 63) >= off) sc += u;
    }
    int wave = tid >> 6;
    if ((tid & 63) == 63) wsum[wave] = sc;
    __syncthreads();
    unsigned wpre = 0;
    for (int w = 0; w < wave; ++w) wpre += wsum[w];
    unsigned excl = wpre + sc - lsum;
    if (i0 + 0 <= NCC2) S[i0 + 0] = excl;
    if (i0 + 1 <= NCC2) S[i0 + 1] = excl + v0;
    if (i0 + 2 <= NCC2) S[i0 + 2] = excl + v0 + v1;
    if (i0 + 3 <= NCC2) S[i0 + 3] = excl + v0 + v1 + v2;
    __syncthreads();

    unsigned T = S[NCC2];
    unsigned Tr = (T + 3u) & ~3u;
    unsigned gb = gbase[b];
    if (tid < 4) {                         // zero the <=3 pad slots
        unsigned q = T + tid;
        if (q < Tr) { if (q < MCAP) stage[q] = 0; else merged[gb + q] = 0; }
    }

    // gather segments -> LDS stage (+ node degree count)
    for (int c = tid; c < NCC2; c += 256) {
        unsigned off = th0s[c], L = lens[c], base = S[c];
        const unsigned* seg = binned + (size_t)c * CHUNK_S + off;
        for (unsigned j = 0; j < L; ++j) {
            unsigned e = seg[j];
            atomicAdd(&cnt[e & (BKT_NODES - 1)], 1u);
            unsigned pos = base + j;
            if (pos < MCAP) stage[pos] = e; else merged[gb + pos] = e;
        }
    }
    __syncthreads();

    // contiguous aligned write-out (gb % 4 == 0)
    unsigned lim = Tr < MCAP ? Tr : MCAP;
    for (unsigned j = tid * 4; j < lim; j += 1024)
        *(uint4*)(merged + gb + j) = *(const uint4*)(stage + j);

    int node = b * BKT_NODES + tid;
    if (tid < BKT_NODES && node < NN) {
        float di = rsqrtf((float)(cnt[tid] + 1u));    // +1 self-loop
        dinv[node] = di;
        p[node] = di * x[node];
    }
}

// ---------- pass 5/6: contiguous-stream aggregation ----------

__global__ __launch_bounds__(256) void k_agg1m(const unsigned* __restrict__ merged,
                                               const unsigned* __restrict__ gbase,
                                               const unsigned* __restrict__ totals,
                                               const float* __restrict__ dinv,
                                               const float* __restrict__ p,
                                               const float* __restrict__ W1,
                                               const float* __restrict__ b1,
                                               const float* __restrict__ W2,
                                               float2* __restrict__ g) {
    __shared__ float acc[BKT_NODES];
    int tid = threadIdx.x, b = blockIdx.x;
    if (tid < BKT_NODES) acc[tid] = 0.f;
    __syncthreads();
    unsigned T = totals[b];
    const unsigned* m = merged + gbase[b];
    for (unsigned j = tid * 4; j < T; j += 1024) {
        uint4 e4 = *(const uint4*)(m + j);
        if (j + 0 < T) atomicAdd(&acc[e4.x & (BKT_NODES - 1)], p[e4.x >> BKT_BITS]);
        if (j + 1 < T) atomicAdd(&acc[e4.y & (BKT_NODES - 1)], p[e4.y >> BKT_BITS]);
        if (j + 2 < T) atomicAdd(&acc[e4.z & (BKT_NODES - 1)], p[e4.z >> BKT_BITS]);
        if (j + 3 < T) atomicAdd(&acc[e4.w & (BKT_NODES - 1)], p[e4.w >> BKT_BITS]);
    }
    __syncthreads();
    int node = b * BKT_NODES + tid;
    if (tid < BKT_NODES && node < NN) {
        float di = dinv[node];
        float s = di * (acc[tid] + p[node]);          // + self-loop
        float g0 = 0.f, g1 = 0.f;
#pragma unroll
        for (int c = 0; c < HC; ++c) {
            float h = fmaxf(fmaf(s, W1[c], b1[c]), 0.f);
            g0 = fmaf(h, W2[2 * c], g0);
            g1 = fmaf(h, W2[2 * c + 1], g1);
        }
        g[node] = make_float2(di * g0, di * g1);
    }
}

__global__ __launch_bounds__(256) void k_agg2m(const unsigned* __restrict__ merged,
                                               const unsigned* __restrict__ gbase,
                                               const unsigned* __restrict__ totals,
                                               const float* __restrict__ dinv,
                                               const float2* __restrict__ g,
                                               const float* __restrict__ b2,
                                               float2* __restrict__ out) {
    __shared__ float ax[BKT_NODES];
    __shared__ float ay[BKT_NODES];
    int tid = threadIdx.x, b = blockIdx.x;
    if (tid < BKT_NODES) { ax[tid] = 0.f; ay[tid] = 0.f; }
    __syncthreads();
    unsigned T = totals[b];
    const unsigned* m = merged + gbase[b];
    for (unsigned j = tid * 4; j < T; j += 1024) {
        uint4 e4 = *(const uint4*)(m + j);
        if (j + 0 < T) { float2 v = g[e4.x >> BKT_BITS]; unsigned l = e4.x & (BKT_NODES - 1);
                         atomicAdd(&ax[l], v.x); atomicAdd(&ay[l], v.y); }
        if (j + 1 < T) { float2 v = g[e4.y >> BKT_BITS]; unsigned l = e4.y & (BKT_NODES - 1);
                         atomicAdd(&ax[l], v.x); atomicAdd(&ay[l], v.y); }
        if (j + 2 < T) { float2 v = g[e4.z >> BKT_BITS]; unsigned l = e4.z & (BKT_NODES - 1);
                         atomicAdd(&ax[l], v.x); atomicAdd(&ay[l], v.y); }
        if (j + 3 < T) { float2 v = g[e4.w >> BKT_BITS]; unsigned l = e4.w & (BKT_NODES - 1);
                         atomicAdd(&ax[l], v.x); atomicAdd(&ay[l], v.y); }
    }
    __syncthreads();
    int node = b * BKT_NODES + tid;
    if (tid < BKT_NODES && node < NN) {
        float di = dinv[node];
        float2 me = g[node];
        out[node] = make_float2(fmaf(di, ax[tid] + me.x, b2[0]),
                                fmaf(di, ay[tid] + me.y, b2[1]));
    }
}

// ---------- fallback: round-1 atomic-scatter path (small ws) ----------

__global__ __launch_bounds__(256) void f_deg(const int* __restrict__ dst,
                                             unsigned int* __restrict__ deg, int E) {
    int i = blockIdx.x * blockDim.x + threadIdx.x;
    if (i < E) atomicAdd(&deg[dst[i]], 1u);
}
__global__ __launch_bounds__(256) void f_node1(const float* __restrict__ x,
                                               const unsigned int* __restrict__ deg,
                                               float* __restrict__ dinv, float* __restrict__ p,
                                               float* __restrict__ t, int N) {
    int i = blockIdx.x * blockDim.x + threadIdx.x;
    if (i < N) {
        float di = rsqrtf((float)(deg[i] + 1u));
        dinv[i] = di; float pi = di * x[i]; p[i] = pi; t[i] = pi;
    }
}
__global__ __launch_bounds__(256) void f_scatter1(const int* __restrict__ src,
                                                  const int* __restrict__ dst,
                                                  const float* __restrict__ p,
                                                  float* __restrict__ t, int E) {
    int i = blockIdx.x * blockDim.x + threadIdx.x;
    if (i < E) atomicAdd(&t[dst[i]], p[src[i]]);
}
__global__ __launch_bounds__(256) void f_node2(const float* __restrict__ dinv,
                                               const float* __restrict__ t,
                                               const float* __restrict__ W1,
                                               const float* __restrict__ b1,
                                               const float* __restrict__ W2,
                                               float2* __restrict__ g,
                                               float2* __restrict__ acc, int N) {
    int i = blockIdx.x * blockDim.x + threadIdx.x;
    if (i < N) {
        float di = dinv[i]; float s = di * t[i];
        float g0 = 0.f, g1 = 0.f;
#pragma unroll
        for (int c = 0; c < HC; ++c) {
            float h = fmaxf(fmaf(s, W1[c], b1[c]), 0.f);
            g0 = fmaf(h, W2[2 * c], g0); g1 = fmaf(h, W2[2 * c + 1], g1);
        }
        float2 gv = make_float2(di * g0, di * g1);
        g[i] = gv; acc[i] = gv;
    }
}
__global__ __launch_bounds__(256) void f_scatter2(const int* __restrict__ src,
                                                  const int* __restrict__ dst,
                                                  const float2* __restrict__ g,
                                                  float* __restrict__ acc, int E) {
    int i = blockIdx.x * blockDim.x + threadIdx.x;
    if (i < E) {
        int s = src[i], d = dst[i];
        float2 gv = g[s];
        atomicAdd(&acc[2 * d], gv.x);
        atomicAdd(&acc[2 * d + 1], gv.y);
    }
}
__global__ __launch_bounds__(256) void f_out(const float* __restrict__ dinv,
                                             const float* __restrict__ b2,
                                             float* __restrict__ out, int N) {
    int i = blockIdx.x * blockDim.x + threadIdx.x;
    if (i < N) {
        float di = dinv[i];
        out[2 * i]     = fmaf(di, out[2 * i],     b2[0]);
        out[2 * i + 1] = fmaf(di, out[2 * i + 1], b2[1]);
    }
}

extern "C" void kernel_launch(void* const* d_in, const int* in_sizes, int n_in,
                              void* d_out, int out_size, void* d_ws, size_t ws_size,
                              hipStream_t stream) {
    const float* x  = (const float*)d_in[0];
    const int* ei   = (const int*)d_in[1];
    const int* src  = ei;
    const int* dst  = ei + NE;
    const float* W1 = (const float*)d_in[2];
    const float* b1 = (const float*)d_in[3];
    const float* W2 = (const float*)d_in[4];
    const float* b2 = (const float*)d_in[5];

    const int BT = 256;
    const int gridE = (NE + BT - 1) / BT;
    const int gridN = (NN + BT - 1) / BT;

    size_t need = 0;
    auto carve = [&](size_t bytes) { size_t o = need; need += (bytes + 255) & ~(size_t)255; return o; };
    size_t o_Hoff = carve((size_t)NCC2 * NB1 * 2);            // 1.22 MB
    size_t o_TH   = carve((size_t)NB1 * NCCP * 2);            // 1.23 MB
    size_t o_tot  = carve((size_t)NB * 4);
    size_t o_gb   = carve((size_t)(NB + 1) * 4);
    size_t o_dinv = carve((size_t)NN * 4);
    size_t o_p    = carve((size_t)NN * 4);
    size_t o_g    = carve((size_t)NN * 8);
    size_t o_bin  = carve((size_t)NCC2 * CHUNK_S * 4);        // 12.8 MB
    size_t o_mrg  = carve((size_t)(NE + 4 * NB + 64) * 4);    // 12.8 MB

    if (ws_size >= need) {
        char* ws = (char*)d_ws;
        unsigned short* Hoff = (unsigned short*)(ws + o_Hoff);
        unsigned short* TH   = (unsigned short*)(ws + o_TH);
        unsigned* totals = (unsigned*)(ws + o_tot);
        unsigned* gbase  = (unsigned*)(ws + o_gb);
        float*    dinv   = (float*)(ws + o_dinv);
        float*    p      = (float*)(ws + o_p);
        float2*   g      = (float2*)(ws + o_g);
        unsigned* binned = (unsigned*)(ws + o_bin);
        unsigned* merged = (unsigned*)(ws + o_mrg);

        k_sortchunk<<<NCC2, 256, 0, stream>>>(src, dst, Hoff, binned);
        k_transT   <<<dim3(25, 25), 256, 0, stream>>>(Hoff, TH);
        k_totals   <<<NB, 64, 0, stream>>>(TH, totals);
        k_base2    <<<1, 1024, 0, stream>>>(totals, gbase);
        k_merge_deg<<<NB, 256, 0, stream>>>(binned, TH, gbase, x, merged, dinv, p);
        k_agg1m    <<<NB, 256, 0, stream>>>(merged, gbase, totals, dinv, p, W1, b1, W2, g);
        k_agg2m    <<<NB, 256, 0, stream>>>(merged, gbase, totals, dinv, g, b2, (float2*)d_out);
    } else {
        float* out = (float*)d_out;
        char* ws = (char*)d_ws;
        unsigned int* deg = (unsigned int*)ws;
        float* dinv = (float*)(ws + 1 * sizeof(float) * NN);
        float* p    = (float*)(ws + 2 * sizeof(float) * NN);
        float* t    = (float*)(ws + 3 * sizeof(float) * NN);
        float2* g   = (float2*)(ws + 4 * sizeof(float) * NN);

        hipMemsetAsync(deg, 0, NN * sizeof(unsigned int), stream);
        f_deg<<<gridE, BT, 0, stream>>>(dst, deg, NE);
        f_node1<<<gridN, BT, 0, stream>>>(x, deg, dinv, p, t, NN);
        f_scatter1<<<gridE, BT, 0, stream>>>(src, dst, p, t, NE);
        f_node2<<<gridN, BT, 0, stream>>>(dinv, t, W1, b1, W2, g, (float2*)out, NN);
        f_scatter2<<<gridE, BT, 0, stream>>>(src, dst, g, out, NE);
        f_out<<<gridN, BT, 0, stream>>>(dinv, b2, out, NN);
    }
}

// Round 8
// 193.418 us; speedup vs baseline: 1.1224x; 1.0018x over previous
//
#include <hip/hip_runtime.h>

#define NN 100000
#define NE 3200000
#define HC 16

#define BKT_BITS 7
#define BKT_NODES 128                 // nodes per bucket
#define NB 782                        // ceil(NN / 128) buckets
#define NB1 783                       // NB + sentinel column
#define CHUNK_S 4096                  // edges per sort block
#define NCC2 782                      // ceil(NE / CHUNK_S)
#define NCCP 784                      // padded TH row stride (u16)
#define MCAP 5120                     // merge LDS stage capacity (max T+pad ~4460)
#define EPAD ((unsigned)NN << BKT_BITS)   // sentinel edge: src=NN (p[NN]=g[NN]=0), slot 0

// ---------- pass 1: per-chunk counting sort ----------

__global__ __launch_bounds__(256) void k_sortchunk(const int* __restrict__ src,
                                                   const int* __restrict__ dst,
                                                   unsigned short* __restrict__ Hoff,
                                                   unsigned* __restrict__ binned) {
    __shared__ unsigned h[NB1];           // hist -> exclusive offsets -> cursors
    __shared__ unsigned sorted[CHUNK_S];  // 16 KB payload staging
    __shared__ unsigned wsum[4];
    int tid = threadIdx.x;
    int c = blockIdx.x;
    int b0 = c * CHUNK_S;
    int e1 = min(b0 + CHUNK_S, NE);
    int cnt = e1 - b0;

    for (int j = tid; j < NB1; j += 256) h[j] = 0;
    __syncthreads();

    for (int v = b0 + tid * 4; v + 3 < e1; v += 1024) {
        int4 d4 = *(const int4*)(dst + v);
        atomicAdd(&h[((unsigned)d4.x) >> BKT_BITS], 1u);
        atomicAdd(&h[((unsigned)d4.y) >> BKT_BITS], 1u);
        atomicAdd(&h[((unsigned)d4.z) >> BKT_BITS], 1u);
        atomicAdd(&h[((unsigned)d4.w) >> BKT_BITS], 1u);
    }
    __syncthreads();

    // block-wide exclusive scan of h[0..NB1)
    int i0 = tid * 4;
    unsigned v0 = (i0 + 0 < NB1) ? h[i0 + 0] : 0;
    unsigned v1 = (i0 + 1 < NB1) ? h[i0 + 1] : 0;
    unsigned v2 = (i0 + 2 < NB1) ? h[i0 + 2] : 0;
    unsigned v3 = (i0 + 3 < NB1) ? h[i0 + 3] : 0;
    unsigned lsum = v0 + v1 + v2 + v3;
    unsigned sc = lsum;
#pragma unroll
    for (int off = 1; off < 64; off <<= 1) {
        unsigned u = __shfl_up(sc, off, 64);
        if ((tid & 63) >= off) sc += u;
    }
    int wave = tid >> 6;
    if ((tid & 63) == 63) wsum[wave] = sc;
    __syncthreads();
    unsigned wpre = 0;
    for (int w = 0; w < wave; ++w) wpre += wsum[w];
    unsigned excl = wpre + sc - lsum;
    __syncthreads();
    if (i0 + 0 < NB1) h[i0 + 0] = excl;
    if (i0 + 1 < NB1) h[i0 + 1] = excl + v0;
    if (i0 + 2 < NB1) h[i0 + 2] = excl + v0 + v1;
    if (i0 + 3 < NB1) h[i0 + 3] = excl + v0 + v1 + v2;

    unsigned short* row = Hoff + (size_t)c * NB1;
    if (i0 + 0 < NB1) row[i0 + 0] = (unsigned short)excl;
    if (i0 + 1 < NB1) row[i0 + 1] = (unsigned short)(excl + v0);
    if (i0 + 2 < NB1) row[i0 + 2] = (unsigned short)(excl + v0 + v1);
    if (i0 + 3 < NB1) row[i0 + 3] = (unsigned short)(excl + v0 + v1 + v2);
    __syncthreads();

    for (int v = b0 + tid * 4; v + 3 < e1; v += 1024) {
        int4 d4 = *(const int4*)(dst + v);
        int4 s4 = *(const int4*)(src + v);
        {   unsigned d = (unsigned)d4.x, s = (unsigned)s4.x;
            unsigned pos = atomicAdd(&h[d >> BKT_BITS], 1u);
            sorted[pos] = (s << BKT_BITS) | (d & (BKT_NODES - 1)); }
        {   unsigned d = (unsigned)d4.y, s = (unsigned)s4.y;
            unsigned pos = atomicAdd(&h[d >> BKT_BITS], 1u);
            sorted[pos] = (s << BKT_BITS) | (d & (BKT_NODES - 1)); }
        {   unsigned d = (unsigned)d4.z, s = (unsigned)s4.z;
            unsigned pos = atomicAdd(&h[d >> BKT_BITS], 1u);
            sorted[pos] = (s << BKT_BITS) | (d & (BKT_NODES - 1)); }
        {   unsigned d = (unsigned)d4.w, s = (unsigned)s4.w;
            unsigned pos = atomicAdd(&h[d >> BKT_BITS], 1u);
            sorted[pos] = (s << BKT_BITS) | (d & (BKT_NODES - 1)); }
    }
    __syncthreads();

    unsigned* out = binned + (size_t)c * CHUNK_S;
    for (int j = tid * 4; j + 3 < cnt; j += 1024)
        *(int4*)(out + j) = *(const int4*)(sorted + j);
}

// ---------- pass 2: transpose Hoff[chunk][bucket] -> TH[bucket][chunk] ----------

__global__ __launch_bounds__(256) void k_transT(const unsigned short* __restrict__ Hoff,
                                                unsigned short* __restrict__ TH) {
    __shared__ unsigned short tile[32][33];
    int tx = threadIdx.x & 31;
    int ty0 = (threadIdx.x >> 5) * 4;
    int c0 = blockIdx.x * 32;
    int b0 = blockIdx.y * 32;
#pragma unroll
    for (int k = 0; k < 4; ++k) {
        int c = c0 + ty0 + k, b = b0 + tx;
        tile[ty0 + k][tx] = (c < NCC2 && b < NB1) ? Hoff[(size_t)c * NB1 + b] : (unsigned short)0;
    }
    __syncthreads();
#pragma unroll
    for (int k = 0; k < 4; ++k) {
        int b = b0 + ty0 + k, c = c0 + tx;
        if (b < NB1 && c < NCC2) TH[(size_t)b * NCCP + c] = tile[tx][ty0 + k];
    }
}

// ---------- pass 3: per-bucket totals + global base scan ----------

__global__ __launch_bounds__(64) void k_totals(const unsigned short* __restrict__ TH,
                                               unsigned* __restrict__ totals) {
    int b = blockIdx.x;
    int lane = threadIdx.x;
    const unsigned short* r0 = TH + (size_t)b * NCCP;
    const unsigned short* r1 = r0 + NCCP;
    unsigned s = 0;
    for (int c = lane; c < NCC2; c += 64) s += (unsigned)r1[c] - (unsigned)r0[c];
#pragma unroll
    for (int off = 32; off >= 1; off >>= 1) s += __shfl_xor(s, off, 64);
    if (lane == 0) totals[b] = s;
}

__global__ __launch_bounds__(1024) void k_base2(const unsigned* __restrict__ totals,
                                                unsigned* __restrict__ gbase) {
    __shared__ unsigned s[1024];
    int t = threadIdx.x;
    unsigned v = (t < NB) ? ((totals[t] + 15u) & ~15u) : 0;   // round16: aligned, pad room
    s[t] = v;
    __syncthreads();
    for (int off = 1; off < 1024; off <<= 1) {
        unsigned u = (t >= off) ? s[t - off] : 0;
        __syncthreads();
        s[t] += u;
        __syncthreads();
    }
    if (t < NB) gbase[t] = s[t] - v;
}

// ---------- pass 4: merge segments -> contiguous per-bucket runs (+16-pad sentinels),
//                    fused degree/dinv/p ----------

__global__ __launch_bounds__(256) void k_merge_deg(const unsigned* __restrict__ binned,
                                                   const unsigned short* __restrict__ TH,
                                                   const unsigned* __restrict__ gbase,
                                                   const float* __restrict__ x,
                                                   unsigned* __restrict__ merged,
                                                   float* __restrict__ dinv,
                                                   float* __restrict__ p) {
    __shared__ unsigned short th0s[NCC2];
    __shared__ unsigned short lens[NCC2];
    __shared__ unsigned S[NB1];            // exclusive scan of lens; S[NCC2] = T
    __shared__ unsigned wsum[4];
    __shared__ unsigned cnt[BKT_NODES];
    __shared__ unsigned stage[MCAP];
    int tid = threadIdx.x, b = blockIdx.x;

    const unsigned short* r0 = TH + (size_t)b * NCCP;
    const unsigned short* r1 = r0 + NCCP;
    for (int c = tid; c < NCC2; c += 256) {
        unsigned a = r0[c];
        th0s[c] = (unsigned short)a;
        lens[c] = (unsigned short)((unsigned)r1[c] - a);
    }
    if (tid < BKT_NODES) cnt[tid] = 0;
    __syncthreads();

    // exclusive scan of lens -> S
    int i0 = tid * 4;
    unsigned v0 = (i0 + 0 < NCC2) ? (unsigned)lens[i0 + 0] : 0;
    unsigned v1 = (i0 + 1 < NCC2) ? (unsigned)lens[i0 + 1] : 0;
    unsigned v2 = (i0 + 2 < NCC2) ? (unsigned)lens[i0 + 2] : 0;
    unsigned v3 = (i0 + 3 < NCC2) ? (unsigned)lens[i0 + 3] : 0;
    unsigned lsum = v0 + v1 + v2 + v3;
    unsigned sc = lsum;
#pragma unroll
    for (int off = 1; off < 64; off <<= 1) {
        unsigned u = __shfl_up(sc, off, 64);
        if ((tid & 63) >= off) sc += u;
    }
    int wave = tid >> 6;
    if ((tid & 63) == 63) wsum[wave] = sc;
    __syncthreads();
    unsigned wpre = 0;
    for (int w = 0; w < wave; ++w) wpre += wsum[w];
    unsigned excl = wpre + sc - lsum;
    if (i0 + 0 <= NCC2) S[i0 + 0] = excl;
    if (i0 + 1 <= NCC2) S[i0 + 1] = excl + v0;
    if (i0 + 2 <= NCC2) S[i0 + 2] = excl + v0 + v1;
    if (i0 + 3 <= NCC2) S[i0 + 3] = excl + v0 + v1 + v2;
    __syncthreads();

    unsigned T = S[NCC2];
    unsigned Tr = (T + 15u) & ~15u;
    unsigned gb = gbase[b];
    if (tid < 16) {                        // sentinel-fill the <=15 pad slots
        unsigned q = T + tid;
        if (q < Tr) stage[q] = EPAD;       // Tr <= MCAP always
    }

    // gather segments -> LDS stage (+ node degree count)
    for (int c = tid; c < NCC2; c += 256) {
        unsigned off = th0s[c], L = lens[c], base = S[c];
        const unsigned* seg = binned + (size_t)c * CHUNK_S + off;
        for (unsigned j = 0; j < L; ++j) {
            unsigned e = seg[j];
            atomicAdd(&cnt[e & (BKT_NODES - 1)], 1u);
            stage[base + j] = e;
        }
    }
    __syncthreads();

    // contiguous aligned write-out (gb % 16 == 0)
    for (unsigned j = tid * 4; j < Tr; j += 1024)
        *(uint4*)(merged + gb + j) = *(const uint4*)(stage + j);

    int node = b * BKT_NODES + tid;
    if (tid < BKT_NODES) {
        if (node < NN) {
            float di = rsqrtf((float)(cnt[tid] + 1u));    // +1 self-loop
            dinv[node] = di;
            p[node] = di * x[node];
        } else if (node == NN) {
            p[node] = 0.f;                 // sentinel target for agg1m
        }
    }
}

// ---------- pass 5/6: guard-free deep-ILP aggregation ----------

__global__ __launch_bounds__(256) void k_agg1m(const unsigned* __restrict__ merged,
                                               const unsigned* __restrict__ gbase,
                                               const unsigned* __restrict__ totals,
                                               const float* __restrict__ dinv,
                                               const float* __restrict__ p,
                                               const float* __restrict__ W1,
                                               const float* __restrict__ b1,
                                               const float* __restrict__ W2,
                                               float2* __restrict__ g) {
    __shared__ float acc[BKT_NODES];
    int tid = threadIdx.x, b = blockIdx.x;
    if (tid < BKT_NODES) acc[tid] = 0.f;
    __syncthreads();
    unsigned Tr = (totals[b] + 15u) & ~15u;
    const unsigned* m = merged + gbase[b];
    for (unsigned j = tid * 16; j < Tr; j += 4096) {
        uint4 ea = *(const uint4*)(m + j);
        uint4 eb = *(const uint4*)(m + j + 4);
        uint4 ec = *(const uint4*)(m + j + 8);
        uint4 ed = *(const uint4*)(m + j + 12);
        float pa0 = p[ea.x >> BKT_BITS], pa1 = p[ea.y >> BKT_BITS];
        float pa2 = p[ea.z >> BKT_BITS], pa3 = p[ea.w >> BKT_BITS];
        float pb0 = p[eb.x >> BKT_BITS], pb1 = p[eb.y >> BKT_BITS];
        float pb2 = p[eb.z >> BKT_BITS], pb3 = p[eb.w >> BKT_BITS];
        float pc0 = p[ec.x >> BKT_BITS], pc1 = p[ec.y >> BKT_BITS];
        float pc2 = p[ec.z >> BKT_BITS], pc3 = p[ec.w >> BKT_BITS];
        float pd0 = p[ed.x >> BKT_BITS], pd1 = p[ed.y >> BKT_BITS];
        float pd2 = p[ed.z >> BKT_BITS], pd3 = p[ed.w >> BKT_BITS];
        atomicAdd(&acc[ea.x & (BKT_NODES - 1)], pa0);
        atomicAdd(&acc[ea.y & (BKT_NODES - 1)], pa1);
        atomicAdd(&acc[ea.z & (BKT_NODES - 1)], pa2);
        atomicAdd(&acc[ea.w & (BKT_NODES - 1)], pa3);
        atomicAdd(&acc[eb.x & (BKT_NODES - 1)], pb0);
        atomicAdd(&acc[eb.y & (BKT_NODES - 1)], pb1);
        atomicAdd(&acc[eb.z & (BKT_NODES - 1)], pb2);
        atomicAdd(&acc[eb.w & (BKT_NODES - 1)], pb3);
        atomicAdd(&acc[ec.x & (BKT_NODES - 1)], pc0);
        atomicAdd(&acc[ec.y & (BKT_NODES - 1)], pc1);
        atomicAdd(&acc[ec.z & (BKT_NODES - 1)], pc2);
        atomicAdd(&acc[ec.w & (BKT_NODES - 1)], pc3);
        atomicAdd(&acc[ed.x & (BKT_NODES - 1)], pd0);
        atomicAdd(&acc[ed.y & (BKT_NODES - 1)], pd1);
        atomicAdd(&acc[ed.z & (BKT_NODES - 1)], pd2);
        atomicAdd(&acc[ed.w & (BKT_NODES - 1)], pd3);
    }
    __syncthreads();
    int node = b * BKT_NODES + tid;
    if (tid < BKT_NODES) {
        if (node < NN) {
            float di = dinv[node];
            float s = di * (acc[tid] + p[node]);          // + self-loop
            float g0 = 0.f, g1 = 0.f;
#pragma unroll
            for (int c = 0; c < HC; ++c) {
                float h = fmaxf(fmaf(s, W1[c], b1[c]), 0.f);
                g0 = fmaf(h, W2[2 * c], g0);
                g1 = fmaf(h, W2[2 * c + 1], g1);
            }
            g[node] = make_float2(di * g0, di * g1);
        } else if (node == NN) {
            g[node] = make_float2(0.f, 0.f);              // sentinel target for agg2m
        }
    }
}

__global__ __launch_bounds__(256) void k_agg2m(const unsigned* __restrict__ merged,
                                               const unsigned* __restrict__ gbase,
                                               const unsigned* __restrict__ totals,
                                               const float* __restrict__ dinv,
                                               const float2* __restrict__ g,
                                               const float* __restrict__ b2,
                                               float2* __restrict__ out) {
    __shared__ float ax[BKT_NODES];
    __shared__ float ay[BKT_NODES];
    int tid = threadIdx.x, b = blockIdx.x;
    if (tid < BKT_NODES) { ax[tid] = 0.f; ay[tid] = 0.f; }
    __syncthreads();
    unsigned Tr = (totals[b] + 15u) & ~15u;
    const unsigned* m = merged + gbase[b];
    for (unsigned j = tid * 16; j < Tr; j += 4096) {
        uint4 ea = *(const uint4*)(m + j);
        uint4 eb = *(const uint4*)(m + j + 4);
        uint4 ec = *(const uint4*)(m + j + 8);
        uint4 ed = *(const uint4*)(m + j + 12);
        float2 va0 = g[ea.x >> BKT_BITS], va1 = g[ea.y >> BKT_BITS];
        float2 va2 = g[ea.z >> BKT_BITS], va3 = g[ea.w >> BKT_BITS];
        float2 vb0 = g[eb.x >> BKT_BITS], vb1 = g[eb.y >> BKT_BITS];
        float2 vb2 = g[eb.z >> BKT_BITS], vb3 = g[eb.w >> BKT_BITS];
        float2 vc0 = g[ec.x >> BKT_BITS], vc1 = g[ec.y >> BKT_BITS];
        float2 vc2 = g[ec.z >> BKT_BITS], vc3 = g[ec.w >> BKT_BITS];
        float2 vd0 = g[ed.x >> BKT_BITS], vd1 = g[ed.y >> BKT_BITS];
        float2 vd2 = g[ed.z >> BKT_BITS], vd3 = g[ed.w >> BKT_BITS];
        unsigned la0 = ea.x & (BKT_NODES - 1), la1 = ea.y & (BKT_NODES - 1);
        unsigned la2 = ea.z & (BKT_NODES - 1), la3 = ea.w & (BKT_NODES - 1);
        unsigned lb0 = eb.x & (BKT_NODES - 1), lb1 = eb.y & (BKT_NODES - 1);
        unsigned lb2 = eb.z & (BKT_NODES - 1), lb3 = eb.w & (BKT_NODES - 1);
        unsigned lc0 = ec.x & (BKT_NODES - 1), lc1 = ec.y & (BKT_NODES - 1);
        unsigned lc2 = ec.z & (BKT_NODES - 1), lc3 = ec.w & (BKT_NODES - 1);
        unsigned ld0 = ed.x & (BKT_NODES - 1), ld1 = ed.y & (BKT_NODES - 1);
        unsigned ld2 = ed.z & (BKT_NODES - 1), ld3 = ed.w & (BKT_NODES - 1);
        atomicAdd(&ax[la0], va0.x); atomicAdd(&ay[la0], va0.y);
        atomicAdd(&ax[la1], va1.x); atomicAdd(&ay[la1], va1.y);
        atomicAdd(&ax[la2], va2.x); atomicAdd(&ay[la2], va2.y);
        atomicAdd(&ax[la3], va3.x); atomicAdd(&ay[la3], va3.y);
        atomicAdd(&ax[lb0], vb0.x); atomicAdd(&ay[lb0], vb0.y);
        atomicAdd(&ax[lb1], vb1.x); atomicAdd(&ay[lb1], vb1.y);
        atomicAdd(&ax[lb2], vb2.x); atomicAdd(&ay[lb2], vb2.y);
        atomicAdd(&ax[lb3], vb3.x); atomicAdd(&ay[lb3], vb3.y);
        atomicAdd(&ax[lc0], vc0.x); atomicAdd(&ay[lc0], vc0.y);
        atomicAdd(&ax[lc1], vc1.x); atomicAdd(&ay[lc1], vc1.y);
        atomicAdd(&ax[lc2], vc2.x); atomicAdd(&ay[lc2], vc2.y);
        atomicAdd(&ax[lc3], vc3.x); atomicAdd(&ay[lc3], vc3.y);
        atomicAdd(&ax[ld0], vd0.x); atomicAdd(&ay[ld0], vd0.y);
        atomicAdd(&ax[ld1], vd1.x); atomicAdd(&ay[ld1], vd1.y);
        atomicAdd(&ax[ld2], vd2.x); atomicAdd(&ay[ld2], vd2.y);
        atomicAdd(&ax[ld3], vd3.x); atomicAdd(&ay[ld3], vd3.y);
    }
    __syncthreads();
    int node = b * BKT_NODES + tid;
    if (tid < BKT_NODES && node < NN) {
        float di = dinv[node];
        float2 me = g[node];
        out[node] = make_float2(fmaf(di, ax[tid] + me.x, b2[0]),
                                fmaf(di, ay[tid] + me.y, b2[1]));
    }
}

// ---------- fallback: round-1 atomic-scatter path (small ws) ----------

__global__ __launch_bounds__(256) void f_deg(const int* __restrict__ dst,
                                             unsigned int* __restrict__ deg, int E) {
    int i = blockIdx.x * blockDim.x + threadIdx.x;
    if (i < E) atomicAdd(&deg[dst[i]], 1u);
}
__global__ __launch_bounds__(256) void f_node1(const float* __restrict__ x,
                                               const unsigned int* __restrict__ deg,
                                               float* __restrict__ dinv, float* __restrict__ p,
                                               float* __restrict__ t, int N) {
    int i = blockIdx.x * blockDim.x + threadIdx.x;
    if (i < N) {
        float di = rsqrtf((float)(deg[i] + 1u));
        dinv[i] = di; float pi = di * x[i]; p[i] = pi; t[i] = pi;
    }
}
__global__ __launch_bounds__(256) void f_scatter1(const int* __restrict__ src,
                                                  const int* __restrict__ dst,
                                                  const float* __restrict__ p,
                                                  float* __restrict__ t, int E) {
    int i = blockIdx.x * blockDim.x + threadIdx.x;
    if (i < E) atomicAdd(&t[dst[i]], p[src[i]]);
}
__global__ __launch_bounds__(256) void f_node2(const float* __restrict__ dinv,
                                               const float* __restrict__ t,
                                               const float* __restrict__ W1,
                                               const float* __restrict__ b1,
                                               const float* __restrict__ W2,
                                               float2* __restrict__ g,
                                               float2* __restrict__ acc, int N) {
    int i = blockIdx.x * blockDim.x + threadIdx.x;
    if (i < N) {
        float di = dinv[i]; float s = di * t[i];
        float g0 = 0.f, g1 = 0.f;
#pragma unroll
        for (int c = 0; c < HC; ++c) {
            float h = fmaxf(fmaf(s, W1[c], b1[c]), 0.f);
            g0 = fmaf(h, W2[2 * c], g0); g1 = fmaf(h, W2[2 * c + 1], g1);
        }
        float2 gv = make_float2(di * g0, di * g1);
        g[i] = gv; acc[i] = gv;
    }
}
__global__ __launch_bounds__(256) void f_scatter2(const int* __restrict__ src,
                                                  const int* __restrict__ dst,
                                                  const float2* __restrict__ g,
                                                  float* __restrict__ acc, int E) {
    int i = blockIdx.x * blockDim.x + threadIdx.x;
    if (i < E) {
        int s = src[i], d = dst[i];
        float2 gv = g[s];
        atomicAdd(&acc[2 * d], gv.x);
        atomicAdd(&acc[2 * d + 1], gv.y);
    }
}
__global__ __launch_bounds__(256) void f_out(const float* __restrict__ dinv,
                                             const float* __restrict__ b2,
                                             float* __restrict__ out, int N) {
    int i = blockIdx.x * blockDim.x + threadIdx.x;
    if (i < N) {
        float di = dinv[i];
        out[2 * i]     = fmaf(di, out[2 * i],     b2[0]);
        out[2 * i + 1] = fmaf(di, out[2 * i + 1], b2[1]);
    }
}

extern "C" void kernel_launch(void* const* d_in, const int* in_sizes, int n_in,
                              void* d_out, int out_size, void* d_ws, size_t ws_size,
                              hipStream_t stream) {
    const float* x  = (const float*)d_in[0];
    const int* ei   = (const int*)d_in[1];
    const int* src  = ei;
    const int* dst  = ei + NE;
    const float* W1 = (const float*)d_in[2];
    const float* b1 = (const float*)d_in[3];
    const float* W2 = (const float*)d_in[4];
    const float* b2 = (const float*)d_in[5];

    const int BT = 256;
    const int gridE = (NE + BT - 1) / BT;
    const int gridN = (NN + BT - 1) / BT;

    size_t need = 0;
    auto carve = [&](size_t bytes) { size_t o = need; need += (bytes + 255) & ~(size_t)255; return o; };
    size_t o_Hoff = carve((size_t)NCC2 * NB1 * 2);            // 1.22 MB
    size_t o_TH   = carve((size_t)NB1 * NCCP * 2);            // 1.23 MB
    size_t o_tot  = carve((size_t)NB * 4);
    size_t o_gb   = carve((size_t)(NB + 1) * 4);
    size_t o_dinv = carve((size_t)NN * 4);
    size_t o_p    = carve((size_t)(NN + 1) * 4);              // +1 sentinel slot
    size_t o_g    = carve((size_t)(NN + 1) * 8);              // +1 sentinel slot
    size_t o_bin  = carve((size_t)NCC2 * CHUNK_S * 4);        // 12.8 MB
    size_t o_mrg  = carve((size_t)(NE + 16 * NB + 64) * 4);   // 12.8 MB + pad

    if (ws_size >= need) {
        char* ws = (char*)d_ws;
        unsigned short* Hoff = (unsigned short*)(ws + o_Hoff);
        unsigned short* TH   = (unsigned short*)(ws + o_TH);
        unsigned* totals = (unsigned*)(ws + o_tot);
        unsigned* gbase  = (unsigned*)(ws + o_gb);
        float*    dinv   = (float*)(ws + o_dinv);
        float*    p      = (float*)(ws + o_p);
        float2*   g      = (float2*)(ws + o_g);
        unsigned* binned = (unsigned*)(ws + o_bin);
        unsigned* merged = (unsigned*)(ws + o_mrg);

        k_sortchunk<<<NCC2, 256, 0, stream>>>(src, dst, Hoff, binned);
        k_transT   <<<dim3(25, 25), 256, 0, stream>>>(Hoff, TH);
        k_totals   <<<NB, 64, 0, stream>>>(TH, totals);
        k_base2    <<<1, 1024, 0, stream>>>(totals, gbase);
        k_merge_deg<<<NB, 256, 0, stream>>>(binned, TH, gbase, x, merged, dinv, p);
        k_agg1m    <<<NB, 256, 0, stream>>>(merged, gbase, totals, dinv, p, W1, b1, W2, g);
        k_agg2m    <<<NB, 256, 0, stream>>>(merged, gbase, totals, dinv, g, b2, (float2*)d_out);
    } else {
        float* out = (float*)d_out;
        char* ws = (char*)d_ws;
        unsigned int* deg = (unsigned int*)ws;
        float* dinv = (float*)(ws + 1 * sizeof(float) * NN);
        float* p    = (float*)(ws + 2 * sizeof(float) * NN);
        float* t    = (float*)(ws + 3 * sizeof(float) * NN);
        float2* g   = (float2*)(ws + 4 * sizeof(float) * NN);

        hipMemsetAsync(deg, 0, NN * sizeof(unsigned int), stream);
        f_deg<<<gridE, BT, 0, stream>>>(dst, deg, NE);
        f_node1<<<gridN, BT, 0, stream>>>(x, deg, dinv, p, t, NN);
        f_scatter1<<<gridE, BT, 0, stream>>>(src, dst, p, t, NE);
        f_node2<<<gridN, BT, 0, stream>>>(dinv, t, W1, b1, W2, g, (float2*)out, NN);
        f_scatter2<<<gridE, BT, 0, stream>>>(src, dst, g, out, NE);
        f_out<<<gridN, BT, 0, stream>>>(dinv, b2, out, NN);
    }
}